// Round 17
// baseline (94.052 us; speedup 1.0000x reference)
//
#include <hip/hip_runtime.h>
#include <math.h>

#define NEG_INF (-3.402823466e38f)

typedef float f32x4 __attribute__((ext_vector_type(4)));
typedef short bf16x8 __attribute__((ext_vector_type(8)));
typedef unsigned int u32x4 __attribute__((ext_vector_type(4)));

__device__ __forceinline__ unsigned short f2bf(float f) {
    unsigned int u = __float_as_uint(f);
    unsigned int r = (u + 0x7FFFu + ((u >> 16) & 1u)) >> 16;
    return (unsigned short)r;
}
__device__ __forceinline__ float bf2f(unsigned short s) {
    return __uint_as_float(((unsigned int)s) << 16);
}
__device__ __forceinline__ unsigned int pack2(float a, float b) {
    return (unsigned int)f2bf(a) | ((unsigned int)f2bf(b) << 16);
}
// x-tile LDS swizzle (rows are 32B): XOR 16B-chunk bits with row&7.
__device__ __forceinline__ int swz(int a) { return a ^ (((a >> 5) & 7) << 4); }

// ---------------- prep: xT (LDS transpose) + B-frags + head frags + fold ----
__global__ __launch_bounds__(256) void prep_kernel(
    const float* __restrict__ x,
    const float* __restrict__ w1, const float* __restrict__ w2,
    const float* __restrict__ w3, const float* __restrict__ w4,
    const float* __restrict__ bn_gamma, const float* __restrict__ bn_beta,
    const float* __restrict__ bn_mean, const float* __restrict__ bn_var,
    const float* __restrict__ lw, const float* __restrict__ lb,
    const float* __restrict__ dw, const float* __restrict__ db,
    unsigned short* __restrict__ xT, unsigned short* __restrict__ Bfrag,
    unsigned short* __restrict__ hfrag, float* __restrict__ bfo,
    float* __restrict__ dbfo)
{
    int bid = blockIdx.x;
    int tid = threadIdx.x;
    if (bid < 288) {
        // ---- xT via LDS transpose: coalesced x reads AND xT writes ----
        __shared__ float xsp[13][257];
        int b = bid / 9;
        int chunk = bid - b * 9;
        int r0 = chunk * 256;            // rows r0..r0+255 (r = t + 20)
        int t = r0 - 20 + tid;
#pragma unroll
        for (int c = 0; c < 13; ++c)
            xsp[c][tid] = (t >= 0 && t < 2048) ? x[((size_t)(b * 13 + c)) * 2048 + t] : 0.f;
        __syncthreads();
        int r = r0 + tid;
        if (r < 2176) {
            unsigned short row[16];
#pragma unroll
            for (int c = 0; c < 13; ++c) row[c] = f2bf(xsp[c][tid]);
            row[13] = 0; row[14] = 0; row[15] = 0;
            u32x4 v0, v1;
            v0.x = row[0] | ((unsigned)row[1] << 16);  v0.y = row[2] | ((unsigned)row[3] << 16);
            v0.z = row[4] | ((unsigned)row[5] << 16);  v0.w = row[6] | ((unsigned)row[7] << 16);
            v1.x = row[8] | ((unsigned)row[9] << 16);  v1.y = row[10] | ((unsigned)row[11] << 16);
            v1.z = row[12] | ((unsigned)row[13] << 16); v1.w = row[14] | ((unsigned)row[15] << 16);
            u32x4* dst = (u32x4*)(xT + ((size_t)b * 2176 + r) * 16);
            dst[0] = v0; dst[1] = v1;
        }
    } else if (bid < 388) {
        // ---- Bfrag: conv weights -> MFMA B-fragment lane layout ----
        int idx = (bid - 288) * 256 + tid;   // frag*64 + lane, < 25600 exact
        int lane = idx & 63, frag = idx >> 6;
        int rel, Kc; const float* w;
        if (frag < 40)       { rel = frag;       w = w1; Kc = 10; }
        else if (frag < 120) { rel = frag - 40;  w = w2; Kc = 20; }
        else if (frag < 240) { rel = frag - 120; w = w3; Kc = 30; }
        else                 { rel = frag - 240; w = w4; Kc = 40; }
        int kh = Kc / 2;
        int ht = rel / kh;
        int k0 = rel - ht * kh;
        int h = ht * 16 + (lane & 15);
        int dk = lane >> 5;
        int cbase = 8 * ((lane >> 4) & 1);
        int k = 2 * k0 + dk;
        unsigned short e[8];
#pragma unroll
        for (int j = 0; j < 8; ++j) {
            int c = cbase + j;
            float v = (c < 13) ? w[((size_t)h * 13 + c) * Kc + k] : 0.f;
            e[j] = f2bf(v);
        }
        u32x4 pk;
        pk.x = e[0] | ((unsigned)e[1] << 16); pk.y = e[2] | ((unsigned)e[3] << 16);
        pk.z = e[4] | ((unsigned)e[5] << 16); pk.w = e[6] | ((unsigned)e[7] << 16);
        *(u32x4*)(Bfrag + (size_t)frag * 512 + lane * 8) = pk;
    } else if (bid == 388) {
        // ---- fold BN shift into head biases (fp32, used post-MFMA) ----
        __shared__ float sh[512];
        for (int j = tid; j < 512; j += 256) {
            float s = rsqrtf(bn_var[j] + 1e-5f) * bn_gamma[j];
            sh[j] = bn_beta[j] - bn_mean[j] * s;
        }
        __syncthreads();
        if (tid < 10) {
            float acc = lb[tid];
            for (int q = 0; q < 512; ++q) acc += sh[q] * lw[tid * 512 + q];
            bfo[tid] = acc;
        } else if (tid == 10) {
            float acc = db[0];
            for (int q = 0; q < 512; ++q) acc += sh[q] * dw[q];
            dbfo[0] = acc;
        }
    } else {
        // ---- hfrag: head weights (BN-scale folded) -> B-frag layout ----
        int idx = (bid - 389) * 256 + tid;   // 16 frags * 64 lanes = 1024 exact
        int lane = idx & 63, frag = idx >> 6;
        int n = lane & 15;
        unsigned short e[8];
#pragma unroll
        for (int jj = 0; jj < 8; ++jj) {
            int k = frag * 32 + 8 * (lane >> 4) + jj;
            float s = rsqrtf(bn_var[k] + 1e-5f) * bn_gamma[k];
            float v = (n < 10) ? lw[n * 512 + k] * s : (n == 10) ? dw[k] * s : 0.f;
            e[jj] = f2bf(v);
        }
        u32x4 pk;
        pk.x = e[0] | ((unsigned)e[1] << 16); pk.y = e[2] | ((unsigned)e[3] << 16);
        pk.z = e[4] | ((unsigned)e[5] << 16); pk.w = e[6] | ((unsigned)e[7] << 16);
        *(u32x4*)(hfrag + (size_t)frag * 512 + lane * 8) = pk;
    }
}

// ---------------- conv via MFMA: depth-3 B prefetch (r15, best: 43 us) -----
__global__ __launch_bounds__(256, 2) void conv_mfma(
    const unsigned short* __restrict__ xT, const unsigned short* __restrict__ Bfrag,
    const float* __restrict__ b1, const float* __restrict__ b2,
    const float* __restrict__ b3, const float* __restrict__ b4,
    unsigned short* __restrict__ feat, unsigned short* __restrict__ totals)
{
    __shared__ __align__(16) unsigned short lds[2688 + 2 * 32 * 132];
    unsigned short* xs = lds;
    unsigned int* stg32 = (unsigned int*)(lds + 2688);   // [32 r2][132 pad] dwords
    const int tid = threadIdx.x;
    const int tq = blockIdx.x & 15;
    const int scale = (blockIdx.x >> 4) & 3;
    const int b = blockIdx.x >> 6;
    const int kh_tab[4] = {5, 10, 15, 20};
    const int so_tab[4] = {0, 40, 120, 240};
    const int KH = kh_tab[scale];
    const int P = 5 * (scale + 1);
    const float* bias = (scale == 0) ? b1 : (scale == 1) ? b2 : (scale == 2) ? b3 : b4;

    const unsigned short* src = xT + ((size_t)b * 2176 + tq * 128) * 16;
#pragma unroll
    for (int it = 0; it < 2; ++it) {
        int c = it * 256 + tid;
        if (c < 336) {
            u32x4 v = *(const u32x4*)(src + c * 8);
            *(u32x4*)((char*)xs + swz(c * 16)) = v;
        }
    }
    __syncthreads();

    const int lane = tid & 63;
    const int wave = tid >> 6;
    const int hgrp = wave & 1;
    const int twq = wave >> 1;
    const int l15 = lane & 15;
    const int g4 = lane >> 4;

    const unsigned short* bfr = Bfrag + ((size_t)(so_tab[scale] + hgrp * 4 * KH)) * 512 + lane * 8;
    float bv[4];
#pragma unroll
    for (int ht = 0; ht < 4; ++ht) bv[ht] = bias[hgrp * 64 + ht * 16 + l15];

    int abase = ((20 - P) + twq * 64 + l15 + (lane >> 5)) * 32 + (g4 & 1) * 16;

    f32x4 acc[4][4];
#pragma unroll
    for (int ht = 0; ht < 4; ++ht)
#pragma unroll
        for (int tt = 0; tt < 4; ++tt)
            acc[ht][tt] = (f32x4){bv[ht], bv[ht], bv[ht], bv[ht]};

#define LOADB(DST, K) \
    _Pragma("unroll") for (int ht_ = 0; ht_ < 4; ++ht_) \
        DST[ht_] = *(const bf16x8*)(bfr + (size_t)(ht_ * KH + (K)) * 512);
#define LOADA(DST, K) \
    _Pragma("unroll") for (int tt_ = 0; tt_ < 4; ++tt_) \
        DST[tt_] = *(const bf16x8*)((const char*)xs + swz(abase + tt_ * 512 + (K) * 64));
#define MFMA16(AA, BB) \
    _Pragma("unroll") for (int ht_ = 0; ht_ < 4; ++ht_) \
        _Pragma("unroll") for (int tt_ = 0; tt_ < 4; ++tt_) \
            acc[ht_][tt_] = __builtin_amdgcn_mfma_f32_16x16x32_bf16(AA[tt_], BB[ht_], acc[ht_][tt_], 0, 0, 0);

    bf16x8 B0[4], B1[4], B2[4], A[4];
    LOADB(B0, 0); LOADB(B1, 1); LOADB(B2, 2);   // KH >= 5: all valid
    int k0 = 0;
#pragma unroll 1
    while (k0 + 3 <= KH) {
        LOADA(A, k0);     MFMA16(A, B0); LOADB(B0, k0 + 3);   // overshoot-ok
        LOADA(A, k0 + 1); MFMA16(A, B1); LOADB(B1, k0 + 4);
        LOADA(A, k0 + 2); MFMA16(A, B2); LOADB(B2, k0 + 5);
        k0 += 3;
    }
    if (k0 < KH)     { LOADA(A, k0);     MFMA16(A, B0); }
    if (k0 + 1 < KH) { LOADA(A, k0 + 1); MFMA16(A, B1); }
#undef LOADB
#undef LOADA
#undef MFMA16

    // ---- cummax scan in-place (acc <- scanned values) ----
    float carry[4] = {NEG_INF, NEG_INF, NEG_INF, NEG_INF};
    const int rq = tq * 2 + twq;
#pragma unroll
    for (int tt = 0; tt < 4; ++tt) {
#pragma unroll
        for (int ht = 0; ht < 4; ++ht) {
            f32x4 v = acc[ht][tt];
            float s0 = v.x;
            float s1 = fmaxf(v.y, s0);
            float s2 = fmaxf(v.z, s1);
            float s3 = fmaxf(v.w, s2);
            float inc = s3;
            float o = __shfl_up(inc, 16); if (lane >= 16) inc = fmaxf(inc, o);
            o = __shfl_up(inc, 32);       if (lane >= 32) inc = fmaxf(inc, o);
            float pre = __shfl_up(inc, 16);
            float base = (lane >= 16) ? fmaxf(carry[ht], pre) : carry[ht];
            s0 = fmaxf(s0, base); s1 = fmaxf(s1, base);
            s2 = fmaxf(s2, base); s3 = fmaxf(s3, base);
            float tot = __shfl(inc, l15 + 48);
            carry[ht] = fmaxf(carry[ht], tot);
            acc[ht][tt] = (f32x4){s0, s1, s2, s3};
        }
    }
    if (lane < 16) {
#pragma unroll
        for (int ht = 0; ht < 4; ++ht) {
            int j = scale * 128 + hgrp * 64 + ht * 16 + l15;
            totals[((size_t)b * 32 + rq) * 512 + j] = f2bf(carry[ht]);
        }
    }

    // ---- 2-half staged transpose: half h = waves with twq==h ----
#pragma unroll 1
    for (int half = 0; half < 2; ++half) {
        if (half) __syncthreads();     // WAR: half-0 readback done
        if (twq == half) {
#pragma unroll
            for (int tt = 0; tt < 4; ++tt) {
#pragma unroll
                for (int ht = 0; ht < 4; ++ht) {
                    f32x4 s = acc[ht][tt];
                    int r2 = tt * 8 + 2 * g4;
                    int cc = hgrp * 64 + ht * 16 + l15;
                    stg32[r2 * 132 + cc]       = pack2(s.x, s.y);
                    stg32[(r2 + 1) * 132 + cc] = pack2(s.z, s.w);
                }
            }
        }
        __syncthreads();               // RAW: stage visible
        size_t grow = (size_t)b * 2048 + tq * 128 + half * 64;
#pragma unroll
        for (int i = 0; i < 2; ++i) {
            int e = i * 256 + tid;     // 0..511 = 32 r2 x 16 q
            int r2 = e >> 4, q = e & 15;
            const unsigned int* p = stg32 + r2 * 132 + q * 8;
            u32x4 da = *(const u32x4*)(p);
            u32x4 dbb = *(const u32x4*)(p + 4);
            u32x4 ev, od;
            ev.x = (da.x & 0xffffu) | (da.y << 16);
            ev.y = (da.z & 0xffffu) | (da.w << 16);
            ev.z = (dbb.x & 0xffffu) | (dbb.y << 16);
            ev.w = (dbb.z & 0xffffu) | (dbb.w << 16);
            od.x = (da.x >> 16) | (da.y & 0xffff0000u);
            od.y = (da.z >> 16) | (da.w & 0xffff0000u);
            od.z = (dbb.x >> 16) | (dbb.y & 0xffff0000u);
            od.w = (dbb.z >> 16) | (dbb.w & 0xffff0000u);
            size_t base = (grow + 2 * r2) * 512 + scale * 128 + q * 8;
            *(u32x4*)(feat + base)       = ev;
            *(u32x4*)(feat + base + 512) = od;
        }
    }
}

// ------ exclusive prefix-max over the 32 t-ranges (validated r3/r5/r15) ----
__global__ void prefix_kernel(const unsigned short* __restrict__ totals,
                              unsigned short* __restrict__ prefix)
{
    int idx = blockIdx.x * 256 + threadIdx.x;   // b*512 + j
    if (idx >= 32 * 512) return;
    int b = idx >> 9, j = idx & 511;
    float run = NEG_INF;
#pragma unroll
    for (int q = 0; q < 32; ++q) {
        prefix[((size_t)b * 32 + q) * 512 + j] = f2bf(run);
        run = fmaxf(run, bf2f(totals[((size_t)b * 32 + q) * 512 + j]));
    }
}

// ---------------- head via MFMA; Bf reused across 4 t-tiles per wave -------
// grid 256 = b(32) x tcq(8). block 256 = 4 waves; wave = one 64t range
// (tc = tcq*4 + wave), iterating 4 sixteen-t sub-tiles with Bf (16KB head
// weights) loaded ONCE -> hfrag traffic 67MB -> 17MB (was equal to feat!).
__global__ __launch_bounds__(256) void head_kernel(
    const unsigned short* __restrict__ feat, const unsigned short* __restrict__ prefix,
    const unsigned short* __restrict__ hfrag, const float* __restrict__ bfo,
    const float* __restrict__ dbfo, float* __restrict__ probs,
    float* __restrict__ delta_raw)
{
    __shared__ float pfs[4][512];
    int b = blockIdx.x >> 3;
    int tcq = blockIdx.x & 7;
    int tid = threadIdx.x;
    int lane = tid & 63;
    int wave = tid >> 6;
    int tc = tcq * 4 + wave;              // this wave's 64t range

    // stage prefix rows for the block's 4 ranges (each 512 bf16)
    for (int e = tid; e < 2048; e += 256) {
        int w = e >> 9, j = e & 511;
        pfs[w][j] = bf2f(prefix[((size_t)b * 32 + tcq * 4 + w) * 512 + j]);
    }
    __syncthreads();

    bf16x8 Bf[16];
#pragma unroll
    for (int k0 = 0; k0 < 16; ++k0)
        Bf[k0] = *(const bf16x8*)(hfrag + (size_t)k0 * 512 + lane * 8);

    const int n = lane & 15;
    const int g4 = lane >> 4;
    float biasv = (n < 10) ? bfo[n] : (n == 10) ? dbfo[0] : 0.f;
    const float* pw = pfs[wave];

#pragma unroll 1
    for (int s = 0; s < 4; ++s) {
        const int tb = tc * 64 + s * 16;
        const unsigned short* fb = feat + ((size_t)b * 2048 + tb + n) * 512 + 8 * g4;
        f32x4 acc = (f32x4){biasv, biasv, biasv, biasv};
#pragma unroll
        for (int k0 = 0; k0 < 16; ++k0) {
            bf16x8 a = *(const bf16x8*)(fb + k0 * 32);
            const float* pp = pw + k0 * 32 + 8 * g4;
            union { unsigned int u[4]; bf16x8 v; } aw;
#pragma unroll
            for (int i = 0; i < 4; ++i) {
                float lo = fmaxf(bf2f((unsigned short)a[2 * i]),     pp[2 * i]);
                float hi = fmaxf(bf2f((unsigned short)a[2 * i + 1]), pp[2 * i + 1]);
                aw.u[i] = (__float_as_uint(lo) >> 16) | (__float_as_uint(hi) & 0xFFFF0000u);
            }
            acc = __builtin_amdgcn_mfma_f32_16x16x32_bf16(aw.v, Bf[k0], acc, 0, 0, 0);
        }
#pragma unroll
        for (int r = 0; r < 4; ++r) {
            float v = acc[r];
            float vm = (n < 10) ? v : NEG_INF;
#pragma unroll
            for (int off = 1; off < 16; off <<= 1)
                vm = fmaxf(vm, __shfl_xor(vm, off, 16));
            float e = (n < 10) ? __expf(v - vm) : 0.f;
            float su = e;
#pragma unroll
            for (int off = 1; off < 16; off <<= 1)
                su += __shfl_xor(su, off, 16);
            int t = tb + g4 * 4 + r;
            if (n < 10) probs[((size_t)b * 2048 + t) * 10 + n] = e / su;
            if (n == 10) delta_raw[b * 2048 + t] = v;
        }
    }
}

// ---------------- softmax over T + budget chain (wave-shfl scans) ----------
__global__ __launch_bounds__(256) void budget_kernel(
    const float* __restrict__ delta_raw, float* __restrict__ pts)
{
    __shared__ float ds[2048];
    __shared__ float red[8];
    int b = blockIdx.x;
    int tid = threadIdx.x;
    int lane = tid & 63, wid = tid >> 6;
    const float* row = delta_raw + b * 2048;
    int base = tid * 8;
    float d[8];
#pragma unroll
    for (int i = 0; i < 8; ++i) d[i] = row[base + i];
    float m = d[0];
#pragma unroll
    for (int i = 1; i < 8; ++i) m = fmaxf(m, d[i]);
#pragma unroll
    for (int off = 1; off < 64; off <<= 1) m = fmaxf(m, __shfl_xor(m, off));
    if (lane == 0) red[wid] = m;
    __syncthreads();
    m = fmaxf(fmaxf(red[0], red[1]), fmaxf(red[2], red[3]));
    float s = 0.f;
#pragma unroll
    for (int i = 0; i < 8; ++i) { d[i] = __expf(d[i] - m); s += d[i]; }
#pragma unroll
    for (int off = 1; off < 64; off <<= 1) s += __shfl_xor(s, off);
    if (lane == 0) red[4 + wid] = s;
    __syncthreads();
    float inv = 1.f / (red[4] + red[5] + red[6] + red[7]);
    float g[8], p = 1.f;
#pragma unroll
    for (int i = 0; i < 8; ++i) {
        d[i] *= inv;
        ds[base + i] = d[i];
        float gv = (base + i == 0) ? 1.f : (1.f - d[i]);
        p *= gv;
        g[i] = p;
    }
    float sp = p;
#pragma unroll
    for (int off = 1; off < 64; off <<= 1) {
        float o = __shfl_up(sp, off);
        if (lane >= off) sp *= o;
    }
    float pre_t = __shfl_up(sp, 1);
    if (lane == 0) pre_t = 1.f;
    if (lane == 63) red[wid] = sp;
    __syncthreads();
    float wpre = 1.f;
#pragma unroll
    for (int w = 0; w < 4; ++w) if (w < wid) wpre *= red[w];
    float pre = wpre * pre_t;
#pragma unroll
    for (int i = 0; i < 8; ++i) {
        int t = base + i;
        float budget = pre * g[i];
        float pt = (t < 2047) ? ds[t + 1] * budget : budget;
        pts[b * 2048 + t] = pt;
    }
}

extern "C" void kernel_launch(void* const* d_in, const int* in_sizes, int n_in,
                              void* d_out, int out_size, void* d_ws, size_t ws_size,
                              hipStream_t stream)
{
    const float* x     = (const float*)d_in[0];
    const float* w1    = (const float*)d_in[1];
    const float* b1    = (const float*)d_in[2];
    const float* w2    = (const float*)d_in[3];
    const float* b2    = (const float*)d_in[4];
    const float* w3    = (const float*)d_in[5];
    const float* b3    = (const float*)d_in[6];
    const float* w4    = (const float*)d_in[7];
    const float* b4    = (const float*)d_in[8];
    const float* gamma = (const float*)d_in[9];
    const float* beta  = (const float*)d_in[10];
    const float* mean  = (const float*)d_in[11];
    const float* var   = (const float*)d_in[12];
    const float* lw    = (const float*)d_in[13];
    const float* lb    = (const float*)d_in[14];
    const float* dw    = (const float*)d_in[15];
    const float* db    = (const float*)d_in[16];

    char* ws = (char*)d_ws;
    unsigned short* feat   = (unsigned short*)ws;                 // 67,108,864 B
    unsigned short* xT     = (unsigned short*)(ws + 67108864);    //  2,228,224 B
    unsigned short* Bfrag  = (unsigned short*)(ws + 69337088);    //    409,600 B
    unsigned short* totals = (unsigned short*)(ws + 69746688);    //  1,048,576 B
    unsigned short* prefix = (unsigned short*)(ws + 70795264);    //  1,048,576 B
    float* draw   = (float*)(ws + 71843840);                      //    262,144 B
    unsigned short* hfrag = (unsigned short*)(ws + 72105984);     //     16,384 B
    float* bfo    = (float*)(ws + 72122368);                      //         64 B
    float* dbfo   = (float*)(ws + 72122432);                      //         64 B

    float* probs = (float*)d_out;
    float* pts   = probs + (size_t)32 * 2048 * 10;

    hipLaunchKernelGGL(prep_kernel, dim3(393), dim3(256), 0, stream,
                       x, w1, w2, w3, w4, gamma, beta, mean, var,
                       lw, lb, dw, db, xT, Bfrag, hfrag, bfo, dbfo);
    hipLaunchKernelGGL(conv_mfma, dim3(2048), dim3(256), 0, stream,
                       xT, Bfrag, b1, b2, b3, b4, feat, totals);
    hipLaunchKernelGGL(prefix_kernel, dim3(64), dim3(256), 0, stream, totals, prefix);
    hipLaunchKernelGGL(head_kernel, dim3(256), dim3(256), 0, stream,
                       feat, prefix, hfrag, bfo, dbfo, probs, draw);
    hipLaunchKernelGGL(budget_kernel, dim3(32), dim3(256), 0, stream, draw, pts);
}

// Round 18
// 80.461 us; speedup vs baseline: 1.1689x; 1.1689x over previous
//
#include <hip/hip_runtime.h>
#include <math.h>

#define NEG_INF (-3.402823466e38f)

typedef float f32x4 __attribute__((ext_vector_type(4)));
typedef short bf16x8 __attribute__((ext_vector_type(8)));
typedef unsigned int u32x4 __attribute__((ext_vector_type(4)));

__device__ __forceinline__ unsigned short f2bf(float f) {
    unsigned int u = __float_as_uint(f);
    unsigned int r = (u + 0x7FFFu + ((u >> 16) & 1u)) >> 16;
    return (unsigned short)r;
}
__device__ __forceinline__ float bf2f(unsigned short s) {
    return __uint_as_float(((unsigned int)s) << 16);
}
__device__ __forceinline__ unsigned int pack2(float a, float b) {
    return (unsigned int)f2bf(a) | ((unsigned int)f2bf(b) << 16);
}
// x-tile LDS swizzle (rows are 32B): XOR 16B-chunk bits with row&7.
__device__ __forceinline__ int swz(int a) { return a ^ (((a >> 5) & 7) << 4); }

// ---------------- prep: xT (LDS transpose) + B-frags + head frags + fold ----
__global__ __launch_bounds__(256) void prep_kernel(
    const float* __restrict__ x,
    const float* __restrict__ w1, const float* __restrict__ w2,
    const float* __restrict__ w3, const float* __restrict__ w4,
    const float* __restrict__ bn_gamma, const float* __restrict__ bn_beta,
    const float* __restrict__ bn_mean, const float* __restrict__ bn_var,
    const float* __restrict__ lw, const float* __restrict__ lb,
    const float* __restrict__ dw, const float* __restrict__ db,
    unsigned short* __restrict__ xT, unsigned short* __restrict__ Bfrag,
    unsigned short* __restrict__ hfrag, float* __restrict__ bfo,
    float* __restrict__ dbfo)
{
    int bid = blockIdx.x;
    int tid = threadIdx.x;
    if (bid < 288) {
        // ---- xT via LDS transpose: coalesced x reads AND xT writes ----
        __shared__ float xsp[13][257];
        int b = bid / 9;
        int chunk = bid - b * 9;
        int r0 = chunk * 256;            // rows r0..r0+255 (r = t + 20)
        int t = r0 - 20 + tid;
#pragma unroll
        for (int c = 0; c < 13; ++c)
            xsp[c][tid] = (t >= 0 && t < 2048) ? x[((size_t)(b * 13 + c)) * 2048 + t] : 0.f;
        __syncthreads();
        int r = r0 + tid;
        if (r < 2176) {
            unsigned short row[16];
#pragma unroll
            for (int c = 0; c < 13; ++c) row[c] = f2bf(xsp[c][tid]);
            row[13] = 0; row[14] = 0; row[15] = 0;
            u32x4 v0, v1;
            v0.x = row[0] | ((unsigned)row[1] << 16);  v0.y = row[2] | ((unsigned)row[3] << 16);
            v0.z = row[4] | ((unsigned)row[5] << 16);  v0.w = row[6] | ((unsigned)row[7] << 16);
            v1.x = row[8] | ((unsigned)row[9] << 16);  v1.y = row[10] | ((unsigned)row[11] << 16);
            v1.z = row[12] | ((unsigned)row[13] << 16); v1.w = row[14] | ((unsigned)row[15] << 16);
            u32x4* dst = (u32x4*)(xT + ((size_t)b * 2176 + r) * 16);
            dst[0] = v0; dst[1] = v1;
        }
    } else if (bid < 388) {
        // ---- Bfrag: conv weights -> MFMA B-fragment lane layout ----
        int idx = (bid - 288) * 256 + tid;   // frag*64 + lane, < 25600 exact
        int lane = idx & 63, frag = idx >> 6;
        int rel, Kc; const float* w;
        if (frag < 40)       { rel = frag;       w = w1; Kc = 10; }
        else if (frag < 120) { rel = frag - 40;  w = w2; Kc = 20; }
        else if (frag < 240) { rel = frag - 120; w = w3; Kc = 30; }
        else                 { rel = frag - 240; w = w4; Kc = 40; }
        int kh = Kc / 2;
        int ht = rel / kh;
        int k0 = rel - ht * kh;
        int h = ht * 16 + (lane & 15);
        int dk = lane >> 5;
        int cbase = 8 * ((lane >> 4) & 1);
        int k = 2 * k0 + dk;
        unsigned short e[8];
#pragma unroll
        for (int j = 0; j < 8; ++j) {
            int c = cbase + j;
            float v = (c < 13) ? w[((size_t)h * 13 + c) * Kc + k] : 0.f;
            e[j] = f2bf(v);
        }
        u32x4 pk;
        pk.x = e[0] | ((unsigned)e[1] << 16); pk.y = e[2] | ((unsigned)e[3] << 16);
        pk.z = e[4] | ((unsigned)e[5] << 16); pk.w = e[6] | ((unsigned)e[7] << 16);
        *(u32x4*)(Bfrag + (size_t)frag * 512 + lane * 8) = pk;
    } else if (bid == 388) {
        // ---- fold BN shift into head biases (fp32, used post-MFMA) ----
        __shared__ float sh[512];
        for (int j = tid; j < 512; j += 256) {
            float s = rsqrtf(bn_var[j] + 1e-5f) * bn_gamma[j];
            sh[j] = bn_beta[j] - bn_mean[j] * s;
        }
        __syncthreads();
        if (tid < 10) {
            float acc = lb[tid];
            for (int q = 0; q < 512; ++q) acc += sh[q] * lw[tid * 512 + q];
            bfo[tid] = acc;
        } else if (tid == 10) {
            float acc = db[0];
            for (int q = 0; q < 512; ++q) acc += sh[q] * dw[q];
            dbfo[0] = acc;
        }
    } else {
        // ---- hfrag: head weights (BN-scale folded) -> B-frag layout ----
        int idx = (bid - 389) * 256 + tid;   // 16 frags * 64 lanes = 1024 exact
        int lane = idx & 63, frag = idx >> 6;
        int n = lane & 15;
        unsigned short e[8];
#pragma unroll
        for (int jj = 0; jj < 8; ++jj) {
            int k = frag * 32 + 8 * (lane >> 4) + jj;
            float s = rsqrtf(bn_var[k] + 1e-5f) * bn_gamma[k];
            float v = (n < 10) ? lw[n * 512 + k] * s : (n == 10) ? dw[k] * s : 0.f;
            e[jj] = f2bf(v);
        }
        u32x4 pk;
        pk.x = e[0] | ((unsigned)e[1] << 16); pk.y = e[2] | ((unsigned)e[3] << 16);
        pk.z = e[4] | ((unsigned)e[5] << 16); pk.w = e[6] | ((unsigned)e[7] << 16);
        *(u32x4*)(hfrag + (size_t)frag * 512 + lane * 8) = pk;
    }
}

// ---------------- conv via MFMA: depth-3 B prefetch + XCD swizzle ----------
// grid 2048; logical id lb = b*64 + scale*16 + tq remapped so each XCD owns
// 4 consecutive b (all scales): its private L2 keeps those xT slices (280KB)
// + full Bfrag (400KB) -> lower B-load hit latency (kernel is latency-bound).
// Bijective since 2048 % 8 == 0 (ERRATA #11 safe).
__global__ __launch_bounds__(256, 2) void conv_mfma(
    const unsigned short* __restrict__ xT, const unsigned short* __restrict__ Bfrag,
    const float* __restrict__ b1, const float* __restrict__ b2,
    const float* __restrict__ b3, const float* __restrict__ b4,
    unsigned short* __restrict__ feat, unsigned short* __restrict__ totals)
{
    __shared__ __align__(16) unsigned short lds[2688 + 2 * 32 * 132];
    unsigned short* xs = lds;
    unsigned int* stg32 = (unsigned int*)(lds + 2688);   // [32 r2][132 pad] dwords
    const int tid = threadIdx.x;
    const int lb = ((blockIdx.x & 7) << 8) + (blockIdx.x >> 3);  // XCD swizzle
    const int tq = lb & 15;
    const int scale = (lb >> 4) & 3;
    const int b = lb >> 6;
    const int kh_tab[4] = {5, 10, 15, 20};
    const int so_tab[4] = {0, 40, 120, 240};
    const int KH = kh_tab[scale];
    const int P = 5 * (scale + 1);
    const float* bias = (scale == 0) ? b1 : (scale == 1) ? b2 : (scale == 2) ? b3 : b4;

    const unsigned short* src = xT + ((size_t)b * 2176 + tq * 128) * 16;
#pragma unroll
    for (int it = 0; it < 2; ++it) {
        int c = it * 256 + tid;
        if (c < 336) {
            u32x4 v = *(const u32x4*)(src + c * 8);
            *(u32x4*)((char*)xs + swz(c * 16)) = v;
        }
    }
    __syncthreads();

    const int lane = tid & 63;
    const int wave = tid >> 6;
    const int hgrp = wave & 1;
    const int twq = wave >> 1;
    const int l15 = lane & 15;
    const int g4 = lane >> 4;

    const unsigned short* bfr = Bfrag + ((size_t)(so_tab[scale] + hgrp * 4 * KH)) * 512 + lane * 8;
    float bv[4];
#pragma unroll
    for (int ht = 0; ht < 4; ++ht) bv[ht] = bias[hgrp * 64 + ht * 16 + l15];

    int abase = ((20 - P) + twq * 64 + l15 + (lane >> 5)) * 32 + (g4 & 1) * 16;

    f32x4 acc[4][4];
#pragma unroll
    for (int ht = 0; ht < 4; ++ht)
#pragma unroll
        for (int tt = 0; tt < 4; ++tt)
            acc[ht][tt] = (f32x4){bv[ht], bv[ht], bv[ht], bv[ht]};

#define LOADB(DST, K) \
    _Pragma("unroll") for (int ht_ = 0; ht_ < 4; ++ht_) \
        DST[ht_] = *(const bf16x8*)(bfr + (size_t)(ht_ * KH + (K)) * 512);
#define LOADA(DST, K) \
    _Pragma("unroll") for (int tt_ = 0; tt_ < 4; ++tt_) \
        DST[tt_] = *(const bf16x8*)((const char*)xs + swz(abase + tt_ * 512 + (K) * 64));
#define MFMA16(AA, BB) \
    _Pragma("unroll") for (int ht_ = 0; ht_ < 4; ++ht_) \
        _Pragma("unroll") for (int tt_ = 0; tt_ < 4; ++tt_) \
            acc[ht_][tt_] = __builtin_amdgcn_mfma_f32_16x16x32_bf16(AA[tt_], BB[ht_], acc[ht_][tt_], 0, 0, 0);

    bf16x8 B0[4], B1[4], B2[4], A[4];
    LOADB(B0, 0); LOADB(B1, 1); LOADB(B2, 2);   // KH >= 5: all valid
    int k0 = 0;
#pragma unroll 1
    while (k0 + 3 <= KH) {
        LOADA(A, k0);     MFMA16(A, B0); LOADB(B0, k0 + 3);   // overshoot-ok
        LOADA(A, k0 + 1); MFMA16(A, B1); LOADB(B1, k0 + 4);
        LOADA(A, k0 + 2); MFMA16(A, B2); LOADB(B2, k0 + 5);
        k0 += 3;
    }
    if (k0 < KH)     { LOADA(A, k0);     MFMA16(A, B0); }
    if (k0 + 1 < KH) { LOADA(A, k0 + 1); MFMA16(A, B1); }
#undef LOADB
#undef LOADA
#undef MFMA16

    // ---- cummax scan in-place (acc <- scanned values) ----
    float carry[4] = {NEG_INF, NEG_INF, NEG_INF, NEG_INF};
    const int rq = tq * 2 + twq;
#pragma unroll
    for (int tt = 0; tt < 4; ++tt) {
#pragma unroll
        for (int ht = 0; ht < 4; ++ht) {
            f32x4 v = acc[ht][tt];
            float s0 = v.x;
            float s1 = fmaxf(v.y, s0);
            float s2 = fmaxf(v.z, s1);
            float s3 = fmaxf(v.w, s2);
            float inc = s3;
            float o = __shfl_up(inc, 16); if (lane >= 16) inc = fmaxf(inc, o);
            o = __shfl_up(inc, 32);       if (lane >= 32) inc = fmaxf(inc, o);
            float pre = __shfl_up(inc, 16);
            float base = (lane >= 16) ? fmaxf(carry[ht], pre) : carry[ht];
            s0 = fmaxf(s0, base); s1 = fmaxf(s1, base);
            s2 = fmaxf(s2, base); s3 = fmaxf(s3, base);
            float tot = __shfl(inc, l15 + 48);
            carry[ht] = fmaxf(carry[ht], tot);
            acc[ht][tt] = (f32x4){s0, s1, s2, s3};
        }
    }
    if (lane < 16) {
#pragma unroll
        for (int ht = 0; ht < 4; ++ht) {
            int j = scale * 128 + hgrp * 64 + ht * 16 + l15;
            totals[((size_t)b * 32 + rq) * 512 + j] = f2bf(carry[ht]);
        }
    }

    // ---- 2-half staged transpose: half h = waves with twq==h ----
#pragma unroll 1
    for (int half = 0; half < 2; ++half) {
        if (half) __syncthreads();     // WAR: half-0 readback done
        if (twq == half) {
#pragma unroll
            for (int tt = 0; tt < 4; ++tt) {
#pragma unroll
                for (int ht = 0; ht < 4; ++ht) {
                    f32x4 s = acc[ht][tt];
                    int r2 = tt * 8 + 2 * g4;
                    int cc = hgrp * 64 + ht * 16 + l15;
                    stg32[r2 * 132 + cc]       = pack2(s.x, s.y);
                    stg32[(r2 + 1) * 132 + cc] = pack2(s.z, s.w);
                }
            }
        }
        __syncthreads();               // RAW: stage visible
        size_t grow = (size_t)b * 2048 + tq * 128 + half * 64;
#pragma unroll
        for (int i = 0; i < 2; ++i) {
            int e = i * 256 + tid;     // 0..511 = 32 r2 x 16 q
            int r2 = e >> 4, q = e & 15;
            const unsigned int* p = stg32 + r2 * 132 + q * 8;
            u32x4 da = *(const u32x4*)(p);
            u32x4 dbb = *(const u32x4*)(p + 4);
            u32x4 ev, od;
            ev.x = (da.x & 0xffffu) | (da.y << 16);
            ev.y = (da.z & 0xffffu) | (da.w << 16);
            ev.z = (dbb.x & 0xffffu) | (dbb.y << 16);
            ev.w = (dbb.z & 0xffffu) | (dbb.w << 16);
            od.x = (da.x >> 16) | (da.y & 0xffff0000u);
            od.y = (da.z >> 16) | (da.w & 0xffff0000u);
            od.z = (dbb.x >> 16) | (dbb.y & 0xffff0000u);
            od.w = (dbb.z >> 16) | (dbb.w & 0xffff0000u);
            size_t base = (grow + 2 * r2) * 512 + scale * 128 + q * 8;
            *(u32x4*)(feat + base)       = ev;
            *(u32x4*)(feat + base + 512) = od;
        }
    }
}

// ------ exclusive prefix-max over the 32 t-ranges (validated r3/r5/r15) ----
__global__ void prefix_kernel(const unsigned short* __restrict__ totals,
                              unsigned short* __restrict__ prefix)
{
    int idx = blockIdx.x * 256 + threadIdx.x;   // b*512 + j
    if (idx >= 32 * 512) return;
    int b = idx >> 9, j = idx & 511;
    float run = NEG_INF;
#pragma unroll
    for (int q = 0; q < 32; ++q) {
        prefix[((size_t)b * 32 + q) * 512 + j] = f2bf(run);
        run = fmaxf(run, bf2f(totals[((size_t)b * 32 + q) * 512 + j]));
    }
}

// ---------------- head via MFMA; prefix precomputed (r15 verbatim) ---------
__global__ __launch_bounds__(256) void head_kernel(
    const unsigned short* __restrict__ feat, const unsigned short* __restrict__ prefix,
    const unsigned short* __restrict__ hfrag, const float* __restrict__ bfo,
    const float* __restrict__ dbfo, float* __restrict__ probs,
    float* __restrict__ delta_raw)
{
    __shared__ float pfs[512];
    int b = blockIdx.x >> 5;
    int tc = blockIdx.x & 31;
    int tid = threadIdx.x;
    int lane = tid & 63;
    int wave = tid >> 6;

    for (int j = tid; j < 512; j += 256)
        pfs[j] = bf2f(prefix[((size_t)b * 32 + tc) * 512 + j]);
    __syncthreads();

    bf16x8 Bf[16];
#pragma unroll
    for (int k0 = 0; k0 < 16; ++k0)
        Bf[k0] = *(const bf16x8*)(hfrag + (size_t)k0 * 512 + lane * 8);

    const int n = lane & 15;
    const int g4 = lane >> 4;
    const int tb = tc * 64 + wave * 16;
    const unsigned short* fb = feat + ((size_t)b * 2048 + tb + n) * 512 + 8 * g4;

    float biasv = (n < 10) ? bfo[n] : (n == 10) ? dbfo[0] : 0.f;
    f32x4 acc = (f32x4){biasv, biasv, biasv, biasv};

#pragma unroll
    for (int k0 = 0; k0 < 16; ++k0) {
        bf16x8 a = *(const bf16x8*)(fb + k0 * 32);
        const float* pp = pfs + k0 * 32 + 8 * g4;
        union { unsigned int u[4]; bf16x8 v; } aw;
#pragma unroll
        for (int i = 0; i < 4; ++i) {
            float lo = fmaxf(bf2f((unsigned short)a[2 * i]),     pp[2 * i]);
            float hi = fmaxf(bf2f((unsigned short)a[2 * i + 1]), pp[2 * i + 1]);
            aw.u[i] = (__float_as_uint(lo) >> 16) | (__float_as_uint(hi) & 0xFFFF0000u);
        }
        acc = __builtin_amdgcn_mfma_f32_16x16x32_bf16(aw.v, Bf[k0], acc, 0, 0, 0);
    }

#pragma unroll
    for (int r = 0; r < 4; ++r) {
        float v = acc[r];
        float vm = (n < 10) ? v : NEG_INF;
#pragma unroll
        for (int off = 1; off < 16; off <<= 1)
            vm = fmaxf(vm, __shfl_xor(vm, off, 16));
        float e = (n < 10) ? __expf(v - vm) : 0.f;
        float s = e;
#pragma unroll
        for (int off = 1; off < 16; off <<= 1)
            s += __shfl_xor(s, off, 16);
        int t = tb + g4 * 4 + r;
        if (n < 10) probs[((size_t)b * 2048 + t) * 10 + n] = e / s;
        if (n == 10) delta_raw[b * 2048 + t] = v;
    }
}

// ---------------- softmax over T + budget chain (wave-shfl scans) ----------
__global__ __launch_bounds__(256) void budget_kernel(
    const float* __restrict__ delta_raw, float* __restrict__ pts)
{
    __shared__ float ds[2048];
    __shared__ float red[8];
    int b = blockIdx.x;
    int tid = threadIdx.x;
    int lane = tid & 63, wid = tid >> 6;
    const float* row = delta_raw + b * 2048;
    int base = tid * 8;
    float d[8];
#pragma unroll
    for (int i = 0; i < 8; ++i) d[i] = row[base + i];
    float m = d[0];
#pragma unroll
    for (int i = 1; i < 8; ++i) m = fmaxf(m, d[i]);
#pragma unroll
    for (int off = 1; off < 64; off <<= 1) m = fmaxf(m, __shfl_xor(m, off));
    if (lane == 0) red[wid] = m;
    __syncthreads();
    m = fmaxf(fmaxf(red[0], red[1]), fmaxf(red[2], red[3]));
    float s = 0.f;
#pragma unroll
    for (int i = 0; i < 8; ++i) { d[i] = __expf(d[i] - m); s += d[i]; }
#pragma unroll
    for (int off = 1; off < 64; off <<= 1) s += __shfl_xor(s, off);
    if (lane == 0) red[4 + wid] = s;
    __syncthreads();
    float inv = 1.f / (red[4] + red[5] + red[6] + red[7]);
    float g[8], p = 1.f;
#pragma unroll
    for (int i = 0; i < 8; ++i) {
        d[i] *= inv;
        ds[base + i] = d[i];
        float gv = (base + i == 0) ? 1.f : (1.f - d[i]);
        p *= gv;
        g[i] = p;
    }
    float sp = p;
#pragma unroll
    for (int off = 1; off < 64; off <<= 1) {
        float o = __shfl_up(sp, off);
        if (lane >= off) sp *= o;
    }
    float pre_t = __shfl_up(sp, 1);
    if (lane == 0) pre_t = 1.f;
    if (lane == 63) red[wid] = sp;
    __syncthreads();
    float wpre = 1.f;
#pragma unroll
    for (int w = 0; w < 4; ++w) if (w < wid) wpre *= red[w];
    float pre = wpre * pre_t;
#pragma unroll
    for (int i = 0; i < 8; ++i) {
        int t = base + i;
        float budget = pre * g[i];
        float pt = (t < 2047) ? ds[t + 1] * budget : budget;
        pts[b * 2048 + t] = pt;
    }
}

extern "C" void kernel_launch(void* const* d_in, const int* in_sizes, int n_in,
                              void* d_out, int out_size, void* d_ws, size_t ws_size,
                              hipStream_t stream)
{
    const float* x     = (const float*)d_in[0];
    const float* w1    = (const float*)d_in[1];
    const float* b1    = (const float*)d_in[2];
    const float* w2    = (const float*)d_in[3];
    const float* b2    = (const float*)d_in[4];
    const float* w3    = (const float*)d_in[5];
    const float* b3    = (const float*)d_in[6];
    const float* w4    = (const float*)d_in[7];
    const float* b4    = (const float*)d_in[8];
    const float* gamma = (const float*)d_in[9];
    const float* beta  = (const float*)d_in[10];
    const float* mean  = (const float*)d_in[11];
    const float* var   = (const float*)d_in[12];
    const float* lw    = (const float*)d_in[13];
    const float* lb    = (const float*)d_in[14];
    const float* dw    = (const float*)d_in[15];
    const float* db    = (const float*)d_in[16];

    char* ws = (char*)d_ws;
    unsigned short* feat   = (unsigned short*)ws;                 // 67,108,864 B
    unsigned short* xT     = (unsigned short*)(ws + 67108864);    //  2,228,224 B
    unsigned short* Bfrag  = (unsigned short*)(ws + 69337088);    //    409,600 B
    unsigned short* totals = (unsigned short*)(ws + 69746688);    //  1,048,576 B
    unsigned short* prefix = (unsigned short*)(ws + 70795264);    //  1,048,576 B
    float* draw   = (float*)(ws + 71843840);                      //    262,144 B
    unsigned short* hfrag = (unsigned short*)(ws + 72105984);     //     16,384 B
    float* bfo    = (float*)(ws + 72122368);                      //         64 B
    float* dbfo   = (float*)(ws + 72122432);                      //         64 B

    float* probs = (float*)d_out;
    float* pts   = probs + (size_t)32 * 2048 * 10;

    hipLaunchKernelGGL(prep_kernel, dim3(393), dim3(256), 0, stream,
                       x, w1, w2, w3, w4, gamma, beta, mean, var,
                       lw, lb, dw, db, xT, Bfrag, hfrag, bfo, dbfo);
    hipLaunchKernelGGL(conv_mfma, dim3(2048), dim3(256), 0, stream,
                       xT, Bfrag, b1, b2, b3, b4, feat, totals);
    hipLaunchKernelGGL(prefix_kernel, dim3(64), dim3(256), 0, stream, totals, prefix);
    hipLaunchKernelGGL(head_kernel, dim3(1024), dim3(256), 0, stream,
                       feat, prefix, hfrag, bfo, dbfo, probs, draw);
    hipLaunchKernelGGL(budget_kernel, dim3(32), dim3(256), 0, stream, draw, pts);
}